// Round 1
// baseline (90.762 us; speedup 1.0000x reference)
//
#include <hip/hip_runtime.h>
#include <cfloat>

// Problem constants (fixed by the reference)
#define N_PTS 65536
#define M_PTS 1024
#define PPT   8                 // threads (chunks) per point
#define CHUNK (M_PTS / PPT)     // 128 maze points per thread

__global__ __launch_bounds__(256) void linearize_kernel(
    const float* __restrict__ ed,   // [N,3] euclidean_data
    const float* __restrict__ mp,   // [M,3] maze_points
    const float* __restrict__ ts,   // [M]   ts_proj
    float* __restrict__ out)        // [N*3] projected_pos ++ [N] linear_pos
{
    const int tid = blockIdx.x * blockDim.x + threadIdx.x;
    const int i = tid >> 3;   // point index
    const int c = tid & 7;    // chunk index within point

    // Query point (8 lanes per group read the same 12 B — L1 broadcast)
    const float x0 = ed[i * 3 + 0];
    const float x1 = ed[i * 3 + 1];
    const float x2 = ed[i * 3 + 2];

    float dmin = FLT_MAX;
    int best = 0;
    const int base = c * CHUNK;

    // Exact-f32, non-contracted math to match the numpy/jax f32 reference
    // bit-for-bit: diff, square, sequential sum over D. Strict '<' keeps the
    // FIRST minimum within the chunk (argmin semantics).
    #pragma unroll 4
    for (int k = 0; k < CHUNK; ++k) {
        const int m = base + k;
        const float dx = __fsub_rn(x0, mp[m * 3 + 0]);
        const float dy = __fsub_rn(x1, mp[m * 3 + 1]);
        const float dz = __fsub_rn(x2, mp[m * 3 + 2]);
        const float d  = __fadd_rn(__fadd_rn(__fmul_rn(dx, dx),
                                             __fmul_rn(dy, dy)),
                                   __fmul_rn(dz, dz));
        if (d < dmin) { dmin = d; best = m; }
    }

    // Reduce (dmin, best) across the 8 chunk-lanes of this point.
    // Tie-break toward the smaller index -> global first-argmin semantics.
    #pragma unroll
    for (int off = 1; off < PPT; off <<= 1) {
        const float od = __shfl_xor(dmin, off);
        const int   ob = __shfl_xor(best, off);
        if (od < dmin || (od == dmin && ob < best)) { dmin = od; best = ob; }
    }

    if (c == 0) {
        // Gathers (L1/L2-resident, 16 B per point total)
        out[i * 3 + 0]     = mp[best * 3 + 0];
        out[i * 3 + 1]     = mp[best * 3 + 1];
        out[i * 3 + 2]     = mp[best * 3 + 2];
        out[N_PTS * 3 + i] = ts[best];
    }
}

extern "C" void kernel_launch(void* const* d_in, const int* in_sizes, int n_in,
                              void* d_out, int out_size, void* d_ws, size_t ws_size,
                              hipStream_t stream) {
    const float* ed = (const float*)d_in[0];
    const float* mp = (const float*)d_in[1];
    const float* ts = (const float*)d_in[2];
    float* out = (float*)d_out;

    const int total_threads = N_PTS * PPT;     // 524288
    const int block = 256;
    const int grid = total_threads / block;    // 2048
    linearize_kernel<<<grid, block, 0, stream>>>(ed, mp, ts, out);
}

// Round 2
// 21.794 us; speedup vs baseline: 4.1645x; 4.1645x over previous
//
#include <hip/hip_runtime.h>
#include <cfloat>

// Problem constants (fixed by the reference)
#define N_PTS 65536
#define M_PTS 1024
#define WAVES_PER_BLOCK 8
#define BLOCK (WAVES_PER_BLOCK * 64)        // 512 threads
#define CHUNK (M_PTS / WAVES_PER_BLOCK)     // 128 maze points per wave

// Each block: 64 points (one per lane), 8 waves each scanning a contiguous
// 128-point maze chunk with WAVE-UNIFORM addresses (scalar-load path),
// then an LDS merge across the 8 waves with first-argmin tie-breaking.
__global__ __launch_bounds__(BLOCK) void linearize_kernel(
    const float* __restrict__ ed,   // [N,3] euclidean_data
    const float* __restrict__ mp,   // [M,3] maze_points
    const float* __restrict__ ts,   // [M]   ts_proj
    float* __restrict__ out)        // [N*3] projected_pos ++ [N] linear_pos
{
    __shared__ float s_dmin[BLOCK];
    __shared__ int   s_best[BLOCK];

    const int lane = threadIdx.x & 63;
    // Force the wave id into an SGPR so the maze-point addresses are
    // provably uniform -> s_load (scalar cache), not 8-line vector loads.
    const int w = __builtin_amdgcn_readfirstlane((int)(threadIdx.x >> 6));
    const int i = blockIdx.x * 64 + lane;   // point index, one per lane

    const float x0 = ed[i * 3 + 0];
    const float x1 = ed[i * 3 + 1];
    const float x2 = ed[i * 3 + 2];

    float dmin = FLT_MAX;
    int best = 0;
    const int m0 = w * CHUNK;
    const float* __restrict__ mpw = mp + (size_t)m0 * 3;

    // Exact-f32, non-contracted math to match the numpy/jax f32 reference
    // bit-for-bit (diff, square, sequential sum over D) so the argmin agrees
    // exactly. Strict '<' keeps the FIRST (smallest-index) minimum.
    #pragma unroll 8
    for (int k = 0; k < CHUNK; ++k) {
        const float p0 = mpw[k * 3 + 0];   // wave-uniform scalar loads
        const float p1 = mpw[k * 3 + 1];
        const float p2 = mpw[k * 3 + 2];
        const float dx = __fsub_rn(x0, p0);
        const float dy = __fsub_rn(x1, p1);
        const float dz = __fsub_rn(x2, p2);
        const float d  = __fadd_rn(__fadd_rn(__fmul_rn(dx, dx),
                                             __fmul_rn(dy, dy)),
                                   __fmul_rn(dz, dz));
        if (d < dmin) { dmin = d; best = m0 + k; }
    }

    s_dmin[threadIdx.x] = dmin;
    s_best[threadIdx.x] = best;
    __syncthreads();

    // Wave 0 merges the 8 per-wave candidates for its 64 points.
    // Chunks are ascending index ranges; tie-break toward the smaller index
    // -> global first-argmin semantics, matching jnp.argmin.
    if (threadIdx.x < 64) {
        #pragma unroll
        for (int j = 1; j < WAVES_PER_BLOCK; ++j) {
            const float od = s_dmin[j * 64 + lane];
            const int   ob = s_best[j * 64 + lane];
            if (od < dmin || (od == dmin && ob < best)) { dmin = od; best = ob; }
        }
        // Gathers are bit-exact copies of maze data -> absmax 0 if argmin matches.
        out[i * 3 + 0]     = mp[best * 3 + 0];
        out[i * 3 + 1]     = mp[best * 3 + 1];
        out[i * 3 + 2]     = mp[best * 3 + 2];
        out[N_PTS * 3 + i] = ts[best];
    }
}

extern "C" void kernel_launch(void* const* d_in, const int* in_sizes, int n_in,
                              void* d_out, int out_size, void* d_ws, size_t ws_size,
                              hipStream_t stream) {
    const float* ed = (const float*)d_in[0];
    const float* mp = (const float*)d_in[1];
    const float* ts = (const float*)d_in[2];
    float* out = (float*)d_out;

    const int grid = N_PTS / 64;   // 1024 blocks x 512 threads = 8192 waves
    linearize_kernel<<<grid, BLOCK, 0, stream>>>(ed, mp, ts, out);
}

// Round 3
// 21.754 us; speedup vs baseline: 4.1722x; 1.0019x over previous
//
#include <hip/hip_runtime.h>
#include <cfloat>

// Problem constants (fixed by the reference)
#define N_PTS 65536
#define M_PTS 1024
#define WAVES_PER_BLOCK 8
#define BLOCK (WAVES_PER_BLOCK * 64)        // 512 threads
#define CHUNK (M_PTS / WAVES_PER_BLOCK)     // 128 maze points per wave

typedef float f32x2 __attribute__((ext_vector_type(2)));
typedef float f32x4 __attribute__((ext_vector_type(4)));

// Block = 64 query points (one per lane) x 8 waves, each wave scanning a
// contiguous 128-point maze chunk. Maze staged in LDS as SoA so the inner
// loop is wave-uniform ds_read_b128 (broadcast) + packed-f32 VALU math.
// All f32 arithmetic is exact and in the reference op order (diff, square,
// sequential sum) with contraction OFF -> bit-identical distances -> exact
// argmin agreement (ties broken toward smaller index at every level).
__global__ __launch_bounds__(BLOCK) void linearize_kernel(
    const float* __restrict__ ed,   // [N,3] euclidean_data
    const float* __restrict__ mp,   // [M,3] maze_points
    const float* __restrict__ ts,   // [M]   ts_proj
    float* __restrict__ out)        // [N*3] projected_pos ++ [N] linear_pos
{
#pragma clang fp contract(off)
    __shared__ float soa[3][M_PTS];     // 12 KB: x[1024], y[1024], z[1024]
    __shared__ float s_dmin[BLOCK];
    __shared__ int   s_best[BLOCK];

    // --- Stage maze points AoS->SoA into LDS (coalesced dword reads) ---
    for (int j = threadIdx.x; j < M_PTS * 3; j += BLOCK) {
        const float v = mp[j];
        soa[j % 3][j / 3] = v;
    }
    __syncthreads();

    const int lane = threadIdx.x & 63;
    const int w = threadIdx.x >> 6;
    const int i = blockIdx.x * 64 + lane;   // query point, one per lane

    const float x0 = ed[i * 3 + 0];
    const float x1 = ed[i * 3 + 1];
    const float x2 = ed[i * 3 + 2];
    const f32x2 vx = {x0, x0};
    const f32x2 vy = {x1, x1};
    const f32x2 vz = {x2, x2};

    float dmin = FLT_MAX;
    int best = 0;
    const int m0 = w * CHUNK;

    #pragma unroll 4
    for (int k = 0; k < CHUNK; k += 4) {
        const int m = m0 + k;
        // Wave-uniform LDS reads: 4 consecutive maze points per dimension.
        const f32x4 px = *(const f32x4*)&soa[0][m];
        const f32x4 py = *(const f32x4*)&soa[1][m];
        const f32x4 pz = *(const f32x4*)&soa[2][m];

        // Pair A = points {m, m+1}, pair B = {m+2, m+3} — packed f32 math,
        // element-wise IEEE exact, contraction disabled.
        const f32x2 dxa = vx - f32x2{px.x, px.y};
        const f32x2 dya = vy - f32x2{py.x, py.y};
        const f32x2 dza = vz - f32x2{pz.x, pz.y};
        const f32x2 da  = (dxa * dxa + dya * dya) + dza * dza;

        const f32x2 dxb = vx - f32x2{px.z, px.w};
        const f32x2 dyb = vy - f32x2{py.z, py.w};
        const f32x2 dzb = vz - f32x2{pz.z, pz.w};
        const f32x2 db  = (dxb * dxb + dyb * dyb) + dzb * dzb;

        // Within-pair select (strict '<' keeps the earlier index on ties).
        const float dA = (da.y < da.x) ? da.y : da.x;
        const int   iA = (da.y < da.x) ? (m + 1) : m;
        const float dB = (db.y < db.x) ? db.y : db.x;
        const int   iB = (db.y < db.x) ? (m + 3) : (m + 2);
        // Cross-pair (B strictly smaller, else keep A = earlier indices).
        const float dC = (dB < dA) ? dB : dA;
        const int   iC = (dB < dA) ? iB : iA;
        // Running (candidate strictly smaller than running min).
        if (dC < dmin) { dmin = dC; best = iC; }
    }

    s_dmin[threadIdx.x] = dmin;
    s_best[threadIdx.x] = best;
    __syncthreads();

    // Wave 0 merges the 8 per-wave candidates for its 64 points.
    // Chunks are ascending index ranges; tie-break toward smaller index
    // -> global first-argmin semantics, matching jnp.argmin.
    if (threadIdx.x < 64) {
        #pragma unroll
        for (int j = 1; j < WAVES_PER_BLOCK; ++j) {
            const float od = s_dmin[j * 64 + lane];
            const int   ob = s_best[j * 64 + lane];
            if (od < dmin || (od == dmin && ob < best)) { dmin = od; best = ob; }
        }
        // Gathers are bit-exact copies of maze data (LDS-resident).
        out[i * 3 + 0]     = soa[0][best];
        out[i * 3 + 1]     = soa[1][best];
        out[i * 3 + 2]     = soa[2][best];
        out[N_PTS * 3 + i] = ts[best];
    }
}

extern "C" void kernel_launch(void* const* d_in, const int* in_sizes, int n_in,
                              void* d_out, int out_size, void* d_ws, size_t ws_size,
                              hipStream_t stream) {
    const float* ed = (const float*)d_in[0];
    const float* mp = (const float*)d_in[1];
    const float* ts = (const float*)d_in[2];
    float* out = (float*)d_out;

    const int grid = N_PTS / 64;   // 1024 blocks x 512 threads = 8192 waves
    linearize_kernel<<<grid, BLOCK, 0, stream>>>(ed, mp, ts, out);
}